// Round 9
// baseline (210.643 us; speedup 1.0000x reference)
//
#include <hip/hip_runtime.h>

// Flash attention fwd. q[B,N,D], k[B,D,N] (=K^T), v[B,N,D] fp32 in, fp32 out.
// B=16, N=2048, D=128. fp16 MFMA (32x32x16), fp32 accumulate.
// R15 (= R9 skeleton, BN 32 -> 64 as 2 sub-tiles per barrier interval):
//  - Producer/consumer split retained (R14 showed inline staging on the
//    consumer critical path loses). 4 consumer + 4 producer waves.
//  - Per interval: qkt(sub0); qkt(sub1); finish(sub0); finish(sub1).
//    Two independent QK MFMA chains + qkt(sub1) overlaps finish(sub0)'s
//    softmax VALU (T15 overlap WITHIN an interval -- nothing carried
//    across barriers, so no R10-R13 spill trap). Barrier count halves.
//  - V swizzle widened to 3-bit sw8 (row stride doubled to 64 f16;
//    sw4 would give 8-way read conflicts, sw8 keeps ~4-way).
//  - Reg budget: consumer peak ~176, producer ~85 (single staging set,
//    write-then-reissue as R14) -- both under the 256 cap.
//  - P^T in registers, exp2-domain softmax, defer-rescale THR=8,
//    setprio on MFMA clusters, XCD swizzle retained from R9.

typedef __attribute__((ext_vector_type(8))) _Float16 f16x8;
typedef __attribute__((ext_vector_type(16))) float f32x16;

constexpr int Bz = 16;
constexpr int Nn = 2048;
constexpr int Dd = 128;
constexpr int BM = 128;  // q rows per block (4 consumer waves x 32)
constexpr int BN = 64;   // keys per interval (2 sub-tiles of 32)

__device__ __forceinline__ int swz(int r) { return (r ^ (r >> 3)) & 7; }
__device__ __forceinline__ int sw8(int d) { return (d ^ (d >> 3)) & 7; }

__device__ __forceinline__ uint pkrtz(float a, float b) {
    return __builtin_bit_cast(uint, __builtin_amdgcn_cvt_pkrtz(a, b));
}

__device__ __forceinline__ float exp2i(float x) {
    return __builtin_amdgcn_exp2f(x);   // raw v_exp_f32 (2^x)
}

__global__ __launch_bounds__(512, 2)
void fattn_kernel(const float* __restrict__ qg,
                  const float* __restrict__ kg,
                  const float* __restrict__ vg,
                  float* __restrict__ og)
{
    __shared__ ushort lds_k[2][BN * Dd];   // [kk][d ^ (swz(kk)<<3)]   2 x 16 KB
    __shared__ ushort lds_v[2][Dd * BN];   // [d][kkpair ^ (sw8(d)<<2)] 2 x 16 KB

    const int bid  = blockIdx.x;           // 256 blocks
    const int xcd  = bid & 7;
    const int idx  = bid >> 3;             // 0..31
    const int b    = xcd * 2 + (idx >> 4);
    const int q0   = (idx & 15) * BM;
    const int tid  = threadIdx.x;
    const int wv   = tid >> 6;             // 0..7
    const int lane = tid & 63;
    const int h    = lane >> 5;            // half-wave (k-slice)
    const int l31  = lane & 31;
    const bool producer = (wv >= 4);

    // ================= producer state =================
    const int ptid = (wv - 4) * 64 + lane;     // 0..255 (producers only)
    const int kgrp = ptid & 7;     // K: n-group (8 n's of 64)
    const int krow = ptid >> 3;    // K: d-pair 0..31 (also +32 -> d 64..127)
    const int vgrp = ptid & 15;    // V: d-group (8 d's of 128)
    const int vrow = ptid >> 4;    // V: kk-pair 0..15 (also +16 -> kk 32..63)
    const float* kbase = kg + (size_t)b * Dd * Nn;
    const float* vbase = vg + (size_t)b * Nn * Dd;
    float4 kr[8], vr[8];   // SINGLE staging set (write tile t+1, then reissue t+2)

    auto issue_loads = [&](int n0) {
        const int d0 = krow * 2;
        const float* s0 = kbase + (size_t)d0 * Nn + n0 + kgrp * 8;
        kr[0] = ((const float4*)s0)[0];
        kr[1] = ((const float4*)s0)[1];
        kr[2] = ((const float4*)(s0 + Nn))[0];
        kr[3] = ((const float4*)(s0 + Nn))[1];
        const float* s1 = s0 + (size_t)64 * Nn;          // d0+64, d0+65
        kr[4] = ((const float4*)s1)[0];
        kr[5] = ((const float4*)s1)[1];
        kr[6] = ((const float4*)(s1 + Nn))[0];
        kr[7] = ((const float4*)(s1 + Nn))[1];
        const int kk0 = vrow * 2;
        const float* t0 = vbase + (size_t)(n0 + kk0) * Dd + vgrp * 8;
        vr[0] = ((const float4*)t0)[0];
        vr[1] = ((const float4*)t0)[1];
        vr[2] = ((const float4*)(t0 + Dd))[0];
        vr[3] = ((const float4*)(t0 + Dd))[1];
        const float* t1 = t0 + (size_t)32 * Dd;          // kk0+32, kk0+33
        vr[4] = ((const float4*)t1)[0];
        vr[5] = ((const float4*)t1)[1];
        vr[6] = ((const float4*)(t1 + Dd))[0];
        vr[7] = ((const float4*)(t1 + Dd))[1];
    };
    auto write_lds = [&](int buf) {
        uint* kw = (uint*)lds_k[buf];
        const float* a0 = (const float*)&kr[0];   // K row d0,   8 n's
        const float* b0 = (const float*)&kr[2];   // K row d0+1
        const float* a1 = (const float*)&kr[4];   // K row d0+64
        const float* b1 = (const float*)&kr[6];   // K row d0+65
        #pragma unroll
        for (int j = 0; j < 8; ++j) {
            const int n = kgrp * 8 + j;           // 0..63
            const int sw = swz(n) << 2;
            kw[n * (Dd / 2) + (krow ^ sw)]        = pkrtz(a0[j], b0[j]);
            kw[n * (Dd / 2) + ((krow + 32) ^ sw)] = pkrtz(a1[j], b1[j]);
        }
        uint* vw = (uint*)lds_v[buf];
        const float* c0 = (const float*)&vr[0];   // V row kk0,  8 d's
        const float* d0v = (const float*)&vr[2];  // V row kk0+1
        const float* c1 = (const float*)&vr[4];   // V row kk0+32
        const float* d1v = (const float*)&vr[6];  // V row kk0+33
        #pragma unroll
        for (int j = 0; j < 8; ++j) {
            const int dd = vgrp * 8 + j;          // 0..127
            const int sv = sw8(dd) << 2;
            vw[dd * (BN / 2) + (vrow ^ sv)]        = pkrtz(c0[j], d0v[j]);
            vw[dd * (BN / 2) + ((vrow + 16) ^ sv)] = pkrtz(c1[j], d1v[j]);
        }
    };

    // ================= consumer state =================
    // Q^T as B-operand: lane holds Q[q = q0+wv*32+l31][d = c*16 + h*8 + j],
    // pre-scaled by log2(e) so softmax runs in exp2 domain.
    f16x8 qf[8];
    if (!producer) {
        const float* qp = qg + (size_t)(b * Nn + q0 + wv * 32 + l31) * Dd + h * 8;
        #pragma unroll
        for (int c = 0; c < 8; ++c) {
            float4 x0 = *(const float4*)(qp + c * 16);
            float4 x1 = *(const float4*)(qp + c * 16 + 4);
            const float xv[8] = {x0.x, x0.y, x0.z, x0.w, x1.x, x1.y, x1.z, x1.w};
            union { f16x8 v; _Float16 e[8]; } u;
            #pragma unroll
            for (int j = 0; j < 8; ++j)
                u.e[j] = (_Float16)(xv[j] * 1.44269504088896340736f);
            qf[c] = u.v;
        }
    }
    f32x16 accO[4];   // O^T[dout = dt*32 + C-row][q = l31]
    #pragma unroll
    for (int dt = 0; dt < 4; ++dt)
        #pragma unroll
        for (int r = 0; r < 16; ++r) accO[dt][r] = 0.f;
    float m_i = -1e30f, l_i = 0.f;   // per-lane (q = l31), log2 domain

    // ---- QK^T for sub-tile s (keys 32s..32s+31 of the interval) ----
    auto qkt = [&](const ushort* kb, int s, f32x16& accS) {
        #pragma unroll
        for (int r = 0; r < 16; ++r) accS[r] = 0.f;
        const int row = s * 32 + l31;
        const int sw = swz(row) << 3;
        __builtin_amdgcn_s_setprio(1);
        #pragma unroll
        for (int c = 0; c < 8; ++c) {
            f16x8 kf = *(const f16x8*)&kb[row * Dd + ((c * 16 + h * 8) ^ sw)];
            accS = __builtin_amdgcn_mfma_f32_32x32x16_f16(kf, qf[c], accS, 0, 0, 0);
        }
        __builtin_amdgcn_s_setprio(0);
    };

    // ---- softmax + P-pack + PV for sub-tile s ----
    auto finish = [&](const ushort* vb, int s, f32x16& accS) {
        // V fragments for kk chunks 2s, 2s+1 (ds_read hides under softmax)
        f16x8 vf[4][2];
        #pragma unroll
        for (int dt = 0; dt < 4; ++dt) {
            const int drow = dt * 32 + l31;
            const int sv = sw8(drow) << 3;
            vf[dt][0] = *(const f16x8*)&vb[drow * BN + (((2 * s) * 16 + 8 * h) ^ sv)];
            vf[dt][1] = *(const f16x8*)&vb[drow * BN + (((2 * s + 1) * 16 + 8 * h) ^ sv)];
        }

        float t0 = fmaxf(accS[0], accS[1]),  t1 = fmaxf(accS[2], accS[3]);
        float t2 = fmaxf(accS[4], accS[5]),  t3 = fmaxf(accS[6], accS[7]);
        float t4 = fmaxf(accS[8], accS[9]),  t5 = fmaxf(accS[10], accS[11]);
        float t6 = fmaxf(accS[12], accS[13]), t7 = fmaxf(accS[14], accS[15]);
        float u0 = fmaxf(t0, t1), u1 = fmaxf(t2, t3);
        float u2 = fmaxf(t4, t5), u3 = fmaxf(t6, t7);
        float mx = fmaxf(fmaxf(u0, u1), fmaxf(u2, u3));
        mx = fmaxf(mx, __shfl_xor(mx, 32, 64));

        // defer-rescale: only pay alpha + 64-mul rescale when max grew >8
        if (!__all(mx <= m_i + 8.f)) {
            const float mn = fmaxf(m_i, mx);
            const float al = exp2i(m_i - mn);
            m_i = mn;
            l_i *= al;
            #pragma unroll
            for (int dt = 0; dt < 4; ++dt)
                #pragma unroll
                for (int r = 0; r < 16; ++r) accO[dt][r] *= al;
        }
        float local = 0.f;
        #pragma unroll
        for (int r = 0; r < 16; ++r) {
            const float p = exp2i(accS[r] - m_i);
            accS[r] = p;
            local += p;
        }
        l_i += local;

        // P^T -> MFMA B-fragments in registers.
        // accS[r] at half h' holds P[kk = 32s + (r&3)+8*(r>>2)+4h'][q=l31].
        const uint pA0 = pkrtz(accS[0],  accS[1]);
        const uint pA1 = pkrtz(accS[2],  accS[3]);
        const uint pB0 = pkrtz(accS[4],  accS[5]);
        const uint pB1 = pkrtz(accS[6],  accS[7]);
        const uint pC0 = pkrtz(accS[8],  accS[9]);
        const uint pC1 = pkrtz(accS[10], accS[11]);
        const uint pD0 = pkrtz(accS[12], accS[13]);
        const uint pD1 = pkrtz(accS[14], accS[15]);
        const uint yA0 = __shfl_xor(pA0, 32, 64);
        const uint yA1 = __shfl_xor(pA1, 32, 64);
        const uint yB0 = __shfl_xor(pB0, 32, 64);
        const uint yB1 = __shfl_xor(pB1, 32, 64);
        const uint yC0 = __shfl_xor(pC0, 32, 64);
        const uint yC1 = __shfl_xor(pC1, 32, 64);
        const uint yD0 = __shfl_xor(pD0, 32, 64);
        const uint yD1 = __shfl_xor(pD1, 32, 64);
        union { uint u[4]; f16x8 v; } P0, P1;
        P0.u[0] = h ? yB0 : pA0;   // kk 32s+8h+0,1  from lower half
        P0.u[1] = h ? yB1 : pA1;
        P0.u[2] = h ? pB0 : yA0;
        P0.u[3] = h ? pB1 : yA1;
        P1.u[0] = h ? yD0 : pC0;   // kk 32s+16+8h+0,1
        P1.u[1] = h ? yD1 : pC1;
        P1.u[2] = h ? pD0 : yC0;
        P1.u[3] = h ? pD1 : yC1;
        const f16x8 pf0 = P0.v, pf1 = P1.v;

        __builtin_amdgcn_s_setprio(1);
        #pragma unroll
        for (int dt = 0; dt < 4; ++dt) {
            accO[dt] = __builtin_amdgcn_mfma_f32_32x32x16_f16(vf[dt][0], pf0, accO[dt], 0, 0, 0);
            accO[dt] = __builtin_amdgcn_mfma_f32_32x32x16_f16(vf[dt][1], pf1, accO[dt], 0, 0, 0);
        }
        __builtin_amdgcn_s_setprio(0);
    };

    f32x16 sS0, sS1;

    // ================= pipeline =================
    if (producer) {
        issue_loads(0);      // tile 0
        write_lds(0);        // (compiler inserts vmcnt wait)
        issue_loads(BN);     // tile 1, in flight across the barrier
    }
    __syncthreads();

    constexpr int ITERS = Nn / BN;   // 32
    for (int it = 0; it < ITERS; it += 2) {
        // even interval: consume buf0; producer writes tile it+1, issues it+2
        if (producer) {
            write_lds(1);
            if (it + 2 < ITERS) issue_loads((it + 2) * BN);
        } else {
            const ushort* kb = lds_k[0];
            const ushort* vb = lds_v[0];
            qkt(kb, 0, sS0);
            qkt(kb, 1, sS1);
            finish(vb, 0, sS0);
            finish(vb, 1, sS1);
        }
        __syncthreads();
        // odd interval: consume buf1; producer writes tile it+2, issues it+3
        if (producer) {
            if (it + 2 < ITERS) write_lds(0);
            if (it + 3 < ITERS) issue_loads((it + 3) * BN);
        } else {
            const ushort* kb = lds_k[1];
            const ushort* vb = lds_v[1];
            qkt(kb, 0, sS0);
            qkt(kb, 1, sS1);
            finish(vb, 0, sS0);
            finish(vb, 1, sS1);
        }
        __syncthreads();
    }

    // ================= epilogue (consumers) =================
    if (!producer) {
        float l = l_i + __shfl_xor(l_i, 32, 64);
        const float inv = 1.f / l;
        float* ob = og + (size_t)(b * Nn + q0 + wv * 32 + l31) * Dd;
        #pragma unroll
        for (int dt = 0; dt < 4; ++dt) {
            #pragma unroll
            for (int g = 0; g < 4; ++g) {
                float4 val;
                val.x = accO[dt][4 * g + 0] * inv;
                val.y = accO[dt][4 * g + 1] * inv;
                val.z = accO[dt][4 * g + 2] * inv;
                val.w = accO[dt][4 * g + 3] * inv;
                *(float4*)(ob + dt * 32 + 8 * g + 4 * h) = val;
            }
        }
    }
}

extern "C" void kernel_launch(void* const* d_in, const int* in_sizes, int n_in,
                              void* d_out, int out_size, void* d_ws, size_t ws_size,
                              hipStream_t stream) {
    const float* q = (const float*)d_in[0];
    const float* k = (const float*)d_in[1];
    const float* v = (const float*)d_in[2];
    float* o = (float*)d_out;
    (void)d_ws; (void)ws_size; (void)in_sizes; (void)n_in; (void)out_size;
    fattn_kernel<<<dim3(Bz * (Nn / BM)), dim3(512), 0, stream>>>(q, k, v, o);
}

// Round 10
// 131.722 us; speedup vs baseline: 1.5991x; 1.5991x over previous
//
#include <hip/hip_runtime.h>

// Flash attention fwd. q[B,N,D], k[B,D,N] (=K^T), v[B,N,D] fp32 in, fp32 out.
// B=16, N=2048, D=128. fp16 MFMA (32x32x16), fp32 accumulate.
// R16 (= R9 EXACTLY, except barrier lowering):
//  - __syncthreads() lowers to "s_waitcnt vmcnt(0) lgkmcnt(0); s_barrier",
//    which drains the producer's JUST-ISSUED tile-(t+2) global loads every
//    interval (~200-900 cy x 64 intervals = the gap between R9's 2500
//    cy/interval and its ~1000 cy of real work). Replace with
//    "s_waitcnt lgkmcnt(0); s_barrier" (raw builtin): ds_writes are made
//    visible, but global loads stay in flight across the barrier and get
//    a full interval to land before write_lds consumes them (counted
//    vmcnt by data dependency). This is T4 (counted vmcnt, never drain).
//  - Safety: consumer's ds_reads all feed MFMAs before the barrier
//    (in-order issue => lgkm-waited); producer ds_writes drained by
//    lgkmcnt(0); in-flight global loads touch only registers.
//  - Everything else identical to R9 (67 us): producer/consumer 4+4,
//    reg double-buffer, P^T in registers, exp2 softmax, defer-rescale.

typedef __attribute__((ext_vector_type(8))) _Float16 f16x8;
typedef __attribute__((ext_vector_type(16))) float f32x16;

constexpr int Bz = 16;
constexpr int Nn = 2048;
constexpr int Dd = 128;
constexpr int BM = 128;  // q rows per block (4 consumer waves x 32)
constexpr int BN = 32;   // keys per iteration

__device__ __forceinline__ int swz(int r) { return (r ^ (r >> 3)) & 7; }
__device__ __forceinline__ int sw4(int d) { return ((d >> 1) ^ (d >> 3)) & 3; }

__device__ __forceinline__ uint pkrtz(float a, float b) {
    return __builtin_bit_cast(uint, __builtin_amdgcn_cvt_pkrtz(a, b));
}

__device__ __forceinline__ float exp2i(float x) {
    return __builtin_amdgcn_exp2f(x);   // raw v_exp_f32 (2^x)
}

// Barrier WITHOUT the vmcnt(0) drain: LDS ops visible, global loads stay
// in flight. The "memory" clobbers fence the compiler on both sides.
__device__ __forceinline__ void bar_lgkm() {
    asm volatile("s_waitcnt lgkmcnt(0)" ::: "memory");
    __builtin_amdgcn_s_barrier();
    asm volatile("" ::: "memory");
}

__global__ __launch_bounds__(512, 2)
void fattn_kernel(const float* __restrict__ qg,
                  const float* __restrict__ kg,
                  const float* __restrict__ vg,
                  float* __restrict__ og)
{
    __shared__ ushort lds_k[2][BN * Dd];   // [kk][d ^ (swz(kk)<<3)]  2 x 8 KB
    __shared__ ushort lds_v[2][Dd * BN];   // [d][kk ^ (sw4(d)<<3)]   2 x 8 KB

    const int bid  = blockIdx.x;           // 256 blocks
    const int xcd  = bid & 7;
    const int idx  = bid >> 3;             // 0..31
    const int b    = xcd * 2 + (idx >> 4);
    const int q0   = (idx & 15) * BM;
    const int tid  = threadIdx.x;
    const int wv   = tid >> 6;             // 0..7
    const int lane = tid & 63;
    const int h    = lane >> 5;            // half-wave (k-slice)
    const int l31  = lane & 31;
    const bool producer = (wv >= 4);

    // ================= producer state =================
    const int ptid = (wv - 4) * 64 + lane;     // 0..255 (producers only)
    const int kgrp = ptid & 3;     // K: n-group (8 n's)
    const int krow = ptid >> 2;    // K: d-pair 0..63
    const int vgrp = ptid & 15;    // V: d-group (8 d's)
    const int vrow = ptid >> 4;    // V: kk-pair 0..15
    const float* kbase = kg + (size_t)b * Dd * Nn;
    const float* vbase = vg + (size_t)b * Nn * Dd;
    float4 kr0[4], vr0[4], kr1[4], vr1[4];   // reg double-buffer (even/odd tiles)

    auto issue_loads = [&](int n0, float4 (&kr)[4], float4 (&vr)[4]) {
        const int d0 = krow * 2;
        const float* s0 = kbase + (size_t)d0 * Nn + n0 + kgrp * 8;
        kr[0] = ((const float4*)s0)[0];
        kr[1] = ((const float4*)s0)[1];
        kr[2] = ((const float4*)(s0 + Nn))[0];
        kr[3] = ((const float4*)(s0 + Nn))[1];
        const int kk0 = vrow * 2;
        const float* t0 = vbase + (size_t)(n0 + kk0) * Dd + vgrp * 8;
        vr[0] = ((const float4*)t0)[0];
        vr[1] = ((const float4*)t0)[1];
        vr[2] = ((const float4*)(t0 + Dd))[0];
        vr[3] = ((const float4*)(t0 + Dd))[1];
    };
    auto write_lds = [&](int buf, const float4 (&kr)[4], const float4 (&vr)[4]) {
        uint* kw = (uint*)lds_k[buf];
        const float* av = (const float*)&kr[0];   // K row d0
        const float* bv = (const float*)&kr[2];   // K row d0+1
        #pragma unroll
        for (int j = 0; j < 8; ++j) {
            const int n = kgrp * 8 + j;
            kw[n * (Dd / 2) + (krow ^ (swz(n) << 2))] = pkrtz(av[j], bv[j]);
        }
        uint* vw = (uint*)lds_v[buf];
        const float* cv = (const float*)&vr[0];   // V row kk0
        const float* dv = (const float*)&vr[2];   // V row kk0+1
        #pragma unroll
        for (int j = 0; j < 8; ++j) {
            const int dd = vgrp * 8 + j;
            vw[dd * (BN / 2) + (vrow ^ (sw4(dd) << 2))] = pkrtz(cv[j], dv[j]);
        }
    };

    // ================= consumer state =================
    // Q^T as B-operand: lane holds Q[q = q0+wv*32+l31][d = c*16 + h*8 + j],
    // pre-scaled by log2(e) so softmax runs in exp2 domain.
    f16x8 qf[8];
    if (!producer) {
        const float* qp = qg + (size_t)(b * Nn + q0 + wv * 32 + l31) * Dd + h * 8;
        #pragma unroll
        for (int c = 0; c < 8; ++c) {
            float4 x0 = *(const float4*)(qp + c * 16);
            float4 x1 = *(const float4*)(qp + c * 16 + 4);
            const float xv[8] = {x0.x, x0.y, x0.z, x0.w, x1.x, x1.y, x1.z, x1.w};
            union { f16x8 v; _Float16 e[8]; } u;
            #pragma unroll
            for (int j = 0; j < 8; ++j)
                u.e[j] = (_Float16)(xv[j] * 1.44269504088896340736f);
            qf[c] = u.v;
        }
    }
    f32x16 accO[4];   // O^T[dout = dt*32 + C-row][q = l31]
    #pragma unroll
    for (int dt = 0; dt < 4; ++dt)
        #pragma unroll
        for (int r = 0; r < 16; ++r) accO[dt][r] = 0.f;
    float m_i = -1e30f, l_i = 0.f;   // per-lane (q = l31), log2 domain

    auto consume = [&](const ushort* kb, const ushort* vb) {
        // ---- S^T[kk=32][q=32] = K' x Q^T, K-dim 128 in 8 chunks ----
        f32x16 accS;
        #pragma unroll
        for (int r = 0; r < 16; ++r) accS[r] = 0.f;
        {
            const int sw = swz(l31) << 3;
            __builtin_amdgcn_s_setprio(1);
            #pragma unroll
            for (int c = 0; c < 8; ++c) {
                f16x8 kf = *(const f16x8*)&kb[l31 * Dd + ((c * 16 + h * 8) ^ sw)];
                accS = __builtin_amdgcn_mfma_f32_32x32x16_f16(kf, qf[c], accS, 0, 0, 0);
            }
            __builtin_amdgcn_s_setprio(0);
        }

        // ---- V fragments early (independent of softmax) ----
        f16x8 vf[4][2];
        #pragma unroll
        for (int dt = 0; dt < 4; ++dt) {
            const int drow = dt * 32 + l31;
            const int sv = sw4(drow) << 3;
            vf[dt][0] = *(const f16x8*)&vb[drow * BN + ((8 * h) ^ sv)];
            vf[dt][1] = *(const f16x8*)&vb[drow * BN + ((16 + 8 * h) ^ sv)];
        }

        // ---- online softmax (exp2 domain), per-lane row (q = l31) ----
        float t0 = fmaxf(accS[0], accS[1]),  t1 = fmaxf(accS[2], accS[3]);
        float t2 = fmaxf(accS[4], accS[5]),  t3 = fmaxf(accS[6], accS[7]);
        float t4 = fmaxf(accS[8], accS[9]),  t5 = fmaxf(accS[10], accS[11]);
        float t6 = fmaxf(accS[12], accS[13]), t7 = fmaxf(accS[14], accS[15]);
        float u0 = fmaxf(t0, t1), u1 = fmaxf(t2, t3);
        float u2 = fmaxf(t4, t5), u3 = fmaxf(t6, t7);
        float mx = fmaxf(fmaxf(u0, u1), fmaxf(u2, u3));
        mx = fmaxf(mx, __shfl_xor(mx, 32, 64));

        // defer-rescale: only pay alpha + 64-mul rescale when max grew >8
        if (!__all(mx <= m_i + 8.f)) {
            const float mn = fmaxf(m_i, mx);
            const float al = exp2i(m_i - mn);
            m_i = mn;
            l_i *= al;
            #pragma unroll
            for (int dt = 0; dt < 4; ++dt)
                #pragma unroll
                for (int r = 0; r < 16; ++r) accO[dt][r] *= al;
        }
        float local = 0.f;
        #pragma unroll
        for (int r = 0; r < 16; ++r) {
            const float p = exp2i(accS[r] - m_i);
            accS[r] = p;
            local += p;
        }
        l_i += local;

        // ---- P^T -> MFMA B-fragments entirely in registers ----
        // accS[r] at half h' holds P[kk=(r&3)+8*(r>>2)+4h'][q=l31].
        const uint pA0 = pkrtz(accS[0],  accS[1]);
        const uint pA1 = pkrtz(accS[2],  accS[3]);
        const uint pB0 = pkrtz(accS[4],  accS[5]);
        const uint pB1 = pkrtz(accS[6],  accS[7]);
        const uint pC0 = pkrtz(accS[8],  accS[9]);
        const uint pC1 = pkrtz(accS[10], accS[11]);
        const uint pD0 = pkrtz(accS[12], accS[13]);
        const uint pD1 = pkrtz(accS[14], accS[15]);
        const uint yA0 = __shfl_xor(pA0, 32, 64);
        const uint yA1 = __shfl_xor(pA1, 32, 64);
        const uint yB0 = __shfl_xor(pB0, 32, 64);
        const uint yB1 = __shfl_xor(pB1, 32, 64);
        const uint yC0 = __shfl_xor(pC0, 32, 64);
        const uint yC1 = __shfl_xor(pC1, 32, 64);
        const uint yD0 = __shfl_xor(pD0, 32, 64);
        const uint yD1 = __shfl_xor(pD1, 32, 64);
        union { uint u[4]; f16x8 v; } P0, P1;
        P0.u[0] = h ? yB0 : pA0;   // kk 8h+0,1  from lower half
        P0.u[1] = h ? yB1 : pA1;   // kk 8h+2,3  from lower half
        P0.u[2] = h ? pB0 : yA0;   // kk 8h+4,5  from upper half
        P0.u[3] = h ? pB1 : yA1;   // kk 8h+6,7  from upper half
        P1.u[0] = h ? yD0 : pC0;   // kk 16+8h+0,1
        P1.u[1] = h ? yD1 : pC1;
        P1.u[2] = h ? pD0 : yC0;
        P1.u[3] = h ? pD1 : yC1;
        const f16x8 pf0 = P0.v, pf1 = P1.v;

        // ---- O^T += V' x P^T : 4 dout tiles x 2 kk-chunks ----
        __builtin_amdgcn_s_setprio(1);
        #pragma unroll
        for (int dt = 0; dt < 4; ++dt) {
            accO[dt] = __builtin_amdgcn_mfma_f32_32x32x16_f16(vf[dt][0], pf0, accO[dt], 0, 0, 0);
            accO[dt] = __builtin_amdgcn_mfma_f32_32x32x16_f16(vf[dt][1], pf1, accO[dt], 0, 0, 0);
        }
        __builtin_amdgcn_s_setprio(0);
    };

    // ================= pipeline =================
    // Tile t: regs issued during iter t-2 (set t&1), LDS-written during
    // iter t-1 (buf t&1), consumed at iter t. Loads get a full barrier
    // interval to land before write_lds waits on them (counted vmcnt via
    // data dependency -- the raw barrier never drains vmcnt to 0).
    if (producer) {
        issue_loads(0,  kr0, vr0);     // tile 0 -> set0
        issue_loads(BN, kr1, vr1);     // tile 1 -> set1 (in flight across barrier)
        write_lds(0, kr0, vr0);        // tile 0 -> buf0
    }
    bar_lgkm();

    constexpr int ITERS = Nn / BN;   // 64
    for (int it = 0; it < ITERS; it += 2) {
        // ---- even iter "it": consumers read buf0 ----
        if (producer) {
            write_lds(1, kr1, vr1);                                // tile it+1 -> buf1
            if (it + 2 < ITERS) issue_loads((it + 2) * BN, kr0, vr0);  // tile it+2 -> set0
        } else {
            consume(lds_k[0], lds_v[0]);
        }
        bar_lgkm();
        // ---- odd iter "it+1": consumers read buf1 ----
        if (producer) {
            if (it + 2 < ITERS) write_lds(0, kr0, vr0);                // tile it+2 -> buf0
            if (it + 3 < ITERS) issue_loads((it + 3) * BN, kr1, vr1);  // tile it+3 -> set1
        } else {
            consume(lds_k[1], lds_v[1]);
        }
        bar_lgkm();
    }

    // ================= epilogue (consumers) =================
    if (!producer) {
        float l = l_i + __shfl_xor(l_i, 32, 64);
        const float inv = 1.f / l;
        float* ob = og + (size_t)(b * Nn + q0 + wv * 32 + l31) * Dd;
        #pragma unroll
        for (int dt = 0; dt < 4; ++dt) {
            #pragma unroll
            for (int g = 0; g < 4; ++g) {
                float4 val;
                val.x = accO[dt][4 * g + 0] * inv;
                val.y = accO[dt][4 * g + 1] * inv;
                val.z = accO[dt][4 * g + 2] * inv;
                val.w = accO[dt][4 * g + 3] * inv;
                *(float4*)(ob + dt * 32 + 8 * g + 4 * h) = val;
            }
        }
    }
}

extern "C" void kernel_launch(void* const* d_in, const int* in_sizes, int n_in,
                              void* d_out, int out_size, void* d_ws, size_t ws_size,
                              hipStream_t stream) {
    const float* q = (const float*)d_in[0];
    const float* k = (const float*)d_in[1];
    const float* v = (const float*)d_in[2];
    float* o = (float*)d_out;
    (void)d_ws; (void)ws_size; (void)in_sizes; (void)n_in; (void)out_size;
    fattn_kernel<<<dim3(Bz * (Nn / BM)), dim3(512), 0, stream>>>(q, k, v, o);
}